// Round 16
// baseline (5808.850 us; speedup 1.0000x reference)
//
#include <hip/hip_runtime.h>
#include <math.h>

#define S_LEN 256
#define BATCH 64
#define EDIM  256
#define HDIM  512

typedef float f32x4 __attribute__((ext_vector_type(4)));

// ---- cache-bypassing (coherence-point) 16B load/store: sc0 sc1 ----
__device__ __forceinline__ void ld_b128_sc(f32x4* v, const float* p) {
  asm volatile("global_load_dwordx4 %0, %1, off sc0 sc1"
               : "=v"(*v) : "v"(p) : "memory");
}
__device__ __forceinline__ void st_b128_sc(float* p, f32x4 v) {
  asm volatile("global_store_dwordx4 %0, %1, off sc0 sc1"
               :: "v"(p), "v"(v) : "memory");
}

// ---------------- Phase A (fallback only): gi = emb[sent] @ Wih^T + bih ----
__global__ __launch_bounds__(512) void gi_gemm(
    const int* __restrict__ sent, const float* __restrict__ emb,
    const float* __restrict__ Wih_f, const float* __restrict__ bih_f,
    const float* __restrict__ Wih_b, const float* __restrict__ bih_b,
    float* __restrict__ gi, int abs_base, int buf_base, int dstride)
{
  const int d  = blockIdx.z;
  const int bx = blockIdx.x;
  const int by = blockIdx.y;
  const float* W    = d ? Wih_b : Wih_f;
  const float* bias = d ? bih_b : bih_f;

  __shared__ int    tok[128];
  __shared__ float4 As4[128][8];
  __shared__ float4 Bs4[128][8];

  const int tid = threadIdx.x;
  if (tid < 128) {
    int s_lc = 2 * bx + (tid >> 6);
    int slot = abs_base + s_lc;
    int srow = (d == 0) ? slot : (S_LEN - 1 - slot);
    tok[tid] = sent[srow * BATCH + (tid & 63)];
  }

  float acc[8][4];
#pragma unroll
  for (int i = 0; i < 8; ++i)
#pragma unroll
    for (int j = 0; j < 4; ++j) acc[i][j] = 0.f;

  const int tb = tid & 15;
  const int tn = tid >> 4;

  for (int kc = 0; kc < 8; ++kc) {
    __syncthreads();
#pragma unroll
    for (int it = 0; it < 2; ++it) {
      int flat = tid + 512 * it;
      int row  = flat >> 3;
      int k4   = flat & 7;
      int sw   = k4 ^ (row & 7) ^ ((row >> 3) & 7);
      As4[row][sw] = *(const float4*)&emb[(size_t)tok[row] * EDIM + kc * 32 + 4 * k4];
      Bs4[row][sw] = *(const float4*)&W[(size_t)(by * 128 + row) * EDIM + kc * 32 + 4 * k4];
    }
    __syncthreads();
#pragma unroll
    for (int k4 = 0; k4 < 8; ++k4) {
      float4 a[8];
#pragma unroll
      for (int i = 0; i < 8; ++i)
        a[i] = As4[8 * tb + i][k4 ^ i ^ (tb & 7)];
#pragma unroll
      for (int j = 0; j < 4; ++j) {
        int r = 4 * tn + j;
        float4 bf = Bs4[r][k4 ^ (r & 7) ^ ((r >> 3) & 7)];
#pragma unroll
        for (int i = 0; i < 8; ++i)
          acc[i][j] += a[i].x * bf.x + a[i].y * bf.y
                     + a[i].z * bf.z + a[i].w * bf.w;
      }
    }
  }

  const int s_lc = 2 * bx + (tb >> 3);
  const int brow = 8 * (tb & 7);
#pragma unroll
  for (int j = 0; j < 4; ++j) {
    int n = by * 128 + 4 * tn + j;
    float bs = bias[n];
    int g = n >> 9, u = n & 511;
    size_t base = ((((size_t)d * dstride + buf_base + s_lc) * 3 + g) * HDIM + u) * BATCH + brow;
    float4 v0 = { acc[0][j] + bs, acc[1][j] + bs, acc[2][j] + bs, acc[3][j] + bs };
    float4 v1 = { acc[4][j] + bs, acc[5][j] + bs, acc[6][j] + bs, acc[7][j] + bs };
    *(float4*)&gi[base]     = v0;
    *(float4*)&gi[base + 4] = v1;
  }
}

#define GBUF ((size_t)2 * 64 * 3 * HDIM * BATCH)   // fallback gi buffer (floats)

// ---------------- Phase B: FULLY-FUSED scan; gi hidden under the dot --------
// 256 WGs x 256 thr, ONE dispatch, no gi workspace. v10: the next step's
// inline-gi (global e-loads + LDS broadcast + FMA, VMEM/VALU-bound) is
// FUSED iteration-by-iteration into the dot-half0 loop (LDS-bound) --
// independent pipes overlap; both accumulation chains keep their exact
// element order -> bitwise-identical outputs (R14/R15 verified 0.0).
// Next-gi lands in gn0..2 and commits to ir/iz/in_ only after this step's
// gate math. gs==0 keeps the standalone gi(1); gs==S_LEN-1 takes plain dot.
__global__ __launch_bounds__(256, 1) void mega_kernel(
    const int* __restrict__ sent, const float* __restrict__ emb,
    const float* __restrict__ Wih_f, const float* __restrict__ bih_f,
    const float* __restrict__ Wih_b, const float* __restrict__ bih_b,
    float* __restrict__ hs,
    const float* __restrict__ Whh_f, const float* __restrict__ bhh_f,
    const float* __restrict__ Whh_b, const float* __restrict__ bhh_b,
    unsigned* cnt)
{
  const int w   = blockIdx.x;
  const int d   = w >> 7;
  const int ub  = w & 127;
  const int tid = threadIdx.x;
  const int tx  = tid & 63;
  const int ty  = __builtin_amdgcn_readfirstlane(tid >> 6);   // 0..3 wave-uniform
  const int u   = 4 * ub + ty;

  const float* Whh = d ? Whh_b : Whh_f;
  const float* bhh = d ? bhh_b : bhh_f;
  const float* Wih = d ? Wih_b : Wih_f;
  const float* bih = d ? bih_b : bih_f;

  __shared__ float whl[12][512];    // Whh rows (24.6 KB)
  __shared__ float wihl[12][256];   // Wih rows (12.3 KB)
  __shared__ float hl[64][260];     // h(t-1), halves sequentially (66.5 KB)
  __shared__ float hb[64][4];

  // stage Whh rows (once)
#pragma unroll
  for (int it = 0; it < 6; ++it) {
    int flat = tid + 256 * it;          // 0..1535 float4s
    int wrow = flat >> 7;
    int c4   = flat & 127;
    int tyw  = wrow / 3, g = wrow % 3;
    *(f32x4*)&whl[wrow][4 * c4] =
        *(const f32x4*)&Whh[(size_t)(g * HDIM + 4 * ub + tyw) * HDIM + 4 * c4];
  }
  // stage Wih rows (once)
#pragma unroll
  for (int it = 0; it < 3; ++it) {
    int flat = tid + 256 * it;          // 0..767 float4s
    int wrow = flat >> 6;
    int c4   = flat & 63;
    int tyw  = wrow / 3, g = wrow % 3;
    *(f32x4*)&wihl[wrow][4 * c4] =
        *(const f32x4*)&Wih[(size_t)(g * HDIM + 4 * ub + tyw) * EDIM + 4 * c4];
  }
  __syncthreads();

  const float br = bhh[u];
  const float bz = bhh[512 + u];
  const float bn = bhh[1024 + u];
  const float bir = bih[u], biz = bih[512 + u], bin = bih[1024 + u];
  const float* wR = &whl[ty * 3 + 0][0];
  const float* wZ = &whl[ty * 3 + 1][0];
  const float* wN = &whl[ty * 3 + 2][0];
  const float* iR = &wihl[ty * 3 + 0][0];
  const float* iZ = &wihl[ty * 3 + 1][0];
  const float* iN = &wihl[ty * 3 + 2][0];
  const int uhalf = u >> 8, ulo = u & 255;
  const int arr_line = (16 * d + (w & 15)) << 4;

  float ir, iz, in_;
#define INLINE_GI(S)                                                        \
  {                                                                         \
    const int srow = (d == 0) ? (S) : (S_LEN - 1 - (S));                    \
    const int tk   = sent[srow * BATCH + tx];                               \
    const float* ep = emb + (size_t)tk * EDIM;                              \
    float g0 = 0.f, g1 = 0.f, g2 = 0.f;                                     \
    _Pragma("unroll 8")                                                     \
    for (int m = 0; m < 64; ++m) {                                          \
      f32x4 e  = *(const f32x4*)&ep[4 * m];                                 \
      f32x4 wa = *(const f32x4*)&iR[4 * m];                                 \
      f32x4 wb = *(const f32x4*)&iZ[4 * m];                                 \
      f32x4 wc = *(const f32x4*)&iN[4 * m];                                 \
      g0 += e.x * wa.x + e.y * wa.y + e.z * wa.z + e.w * wa.w;              \
      g1 += e.x * wb.x + e.y * wb.y + e.z * wb.z + e.w * wb.w;              \
      g2 += e.x * wc.x + e.y * wc.y + e.z * wc.z + e.w * wc.w;              \
    }                                                                       \
    ir = g0 + bir; iz = g1 + biz; in_ = g2 + bin;                           \
  }

  INLINE_GI(0)                         // step 0's gi, in registers

  for (int gs = 0; gs < S_LEN; ++gs) {
    const int t_store = (d == 0) ? gs : (S_LEN - 1 - gs);
    const int t_prev  = (d == 0) ? (gs - 1) : (S_LEN - gs);

    float aR = 0.f, aZ = 0.f, aN = 0.f, hp = 0.f;
    float gn0 = 0.f, gn1 = 0.f, gn2 = 0.f;
    bool have_gn = false;

    if (gs > 0) {
      const float* hpg = hs + ((size_t)d * S_LEN + t_prev) * HDIM * BATCH;
      f32x4 buf[32];
#pragma unroll
      for (int j = 0; j < 32; ++j) {
        int half = j >> 4;
        int flat = tid + 256 * (j & 15);
        ld_b128_sc(&buf[j], &hpg[(size_t)(flat >> 6) * HDIM + half * 256 + 4 * (flat & 63)]);
      }
      asm volatile("s_waitcnt vmcnt(16)" ::: "memory");   // half 0 arrived
      __builtin_amdgcn_sched_barrier(0);
#pragma unroll
      for (int j = 0; j < 16; ++j) {
        int flat = tid + 256 * j;
        *(f32x4*)&hl[flat >> 6][4 * (flat & 63)] = buf[j];
      }
      __syncthreads();

      if (uhalf == 0) hp = hl[tx][ulo];
      {
        const float* hrow = &hl[tx][0];
        if (gs + 1 < S_LEN) {
          // ---- FUSED dot-half0 + gi(gs+1): independent chains, exact orders
          const int srow = (d == 0) ? (gs + 1) : (S_LEN - 2 - gs);
          const int tk   = sent[srow * BATCH + tx];
          const float* ep = emb + (size_t)tk * EDIM;
#pragma unroll 4
          for (int m = 0; m < 64; ++m) {
            f32x4 h4  = *(const f32x4*)&hrow[4 * m];
            f32x4 w4r = *(const f32x4*)&wR[4 * m];
            f32x4 w4z = *(const f32x4*)&wZ[4 * m];
            f32x4 w4n = *(const f32x4*)&wN[4 * m];
            aR += h4.x * w4r.x + h4.y * w4r.y + h4.z * w4r.z + h4.w * w4r.w;
            aZ += h4.x * w4z.x + h4.y * w4z.y + h4.z * w4z.z + h4.w * w4z.w;
            aN += h4.x * w4n.x + h4.y * w4n.y + h4.z * w4n.z + h4.w * w4n.w;
            f32x4 e  = *(const f32x4*)&ep[4 * m];
            f32x4 wa = *(const f32x4*)&iR[4 * m];
            f32x4 wb = *(const f32x4*)&iZ[4 * m];
            f32x4 wc = *(const f32x4*)&iN[4 * m];
            gn0 += e.x * wa.x + e.y * wa.y + e.z * wa.z + e.w * wa.w;
            gn1 += e.x * wb.x + e.y * wb.y + e.z * wb.z + e.w * wb.w;
            gn2 += e.x * wc.x + e.y * wc.y + e.z * wc.z + e.w * wc.w;
          }
          have_gn = true;
        } else {
          // plain dot-half0 (last step)
#pragma unroll 4
          for (int kk = 0; kk < 256; kk += 4) {
            f32x4 h4  = *(const f32x4*)&hrow[kk];
            f32x4 w4r = *(const f32x4*)&wR[kk];
            f32x4 w4z = *(const f32x4*)&wZ[kk];
            f32x4 w4n = *(const f32x4*)&wN[kk];
            aR += h4.x * w4r.x + h4.y * w4r.y + h4.z * w4r.z + h4.w * w4r.w;
            aZ += h4.x * w4z.x + h4.y * w4z.y + h4.z * w4z.z + h4.w * w4z.w;
            aN += h4.x * w4n.x + h4.y * w4n.y + h4.z * w4n.z + h4.w * w4n.w;
          }
        }
      }
      __syncthreads();                                    // half-0 reads done
      asm volatile("s_waitcnt vmcnt(0)" ::: "memory");    // half 1 arrived
      __builtin_amdgcn_sched_barrier(0);
#pragma unroll
      for (int j = 16; j < 32; ++j) {
        int flat = tid + 256 * (j & 15);
        *(f32x4*)&hl[flat >> 6][4 * (flat & 63)] = buf[j];
      }
      __syncthreads();

      if (uhalf == 1) hp = hl[tx][ulo];
      {
        const float* hrow = &hl[tx][0];
#pragma unroll 4
        for (int kk = 0; kk < 256; kk += 4) {
          f32x4 h4  = *(const f32x4*)&hrow[kk];
          f32x4 w4r = *(const f32x4*)&wR[256 + kk];
          f32x4 w4z = *(const f32x4*)&wZ[256 + kk];
          f32x4 w4n = *(const f32x4*)&wN[256 + kk];
          aR += h4.x * w4r.x + h4.y * w4r.y + h4.z * w4r.z + h4.w * w4r.w;
          aZ += h4.x * w4z.x + h4.y * w4z.y + h4.z * w4z.z + h4.w * w4z.w;
          aN += h4.x * w4n.x + h4.y * w4n.y + h4.z * w4n.z + h4.w * w4n.w;
        }
      }
    }

    float r  = 1.f / (1.f + expf(-(ir + aR + br)));
    float zg = 1.f / (1.f + expf(-(iz + aZ + bz)));
    float n  = tanhf(in_ + r * (aN + bn));
    float hn = (1.f - zg) * n + zg * hp;

    // commit next step's gi (computed in the fused loop)
    if (have_gn) { ir = gn0 + bir; iz = gn1 + biz; in_ = gn2 + bin; }

    __syncthreads();
    hb[tx][ty] = hn;
    __syncthreads();
    if (tid < 64) {
      f32x4 v = *(const f32x4*)&hb[tid][0];
      st_b128_sc(&hs[(((size_t)d * S_LEN + t_store) * BATCH + tid) * HDIM + 4 * ub], v);
      asm volatile("s_waitcnt vmcnt(0)" ::: "memory");
    }
    if (tid == 0)
      __hip_atomic_fetch_add(&cnt[arr_line], 1u,
                             __ATOMIC_RELAXED, __HIP_MEMORY_SCOPE_AGENT);

    if (gs == 0) INLINE_GI(1)          // only step 0 lacks a dot to fuse into

    // per-direction barrier poll
    if (tid < 16) {
      unsigned tgt = 8u * (unsigned)(gs + 1);
      while (__hip_atomic_load(&cnt[(16 * d + tid) << 4],
                               __ATOMIC_RELAXED, __HIP_MEMORY_SCOPE_AGENT) < tgt)
        __builtin_amdgcn_s_sleep(1);
    }
    __syncthreads();
  }
#undef INLINE_GI
}

// ---------------- Fallback classic scan (R8/R13) for small ws ----------------
__global__ __launch_bounds__(256, 1) void scan_kernel(
    const float* __restrict__ gi, float* __restrict__ hs,
    const float* __restrict__ Whh_f, const float* __restrict__ bhh_f,
    const float* __restrict__ Whh_b, const float* __restrict__ bhh_b,
    unsigned* cnt, int step0, int nsteps)
{
  const int w   = blockIdx.x;
  const int d   = w >> 7;
  const int ub  = w & 127;
  const int tid = threadIdx.x;
  const int tx  = tid & 63;
  const int ty  = __builtin_amdgcn_readfirstlane(tid >> 6);
  const int u   = 4 * ub + ty;

  const float* Whh = d ? Whh_b : Whh_f;
  const float* bhh = d ? bhh_b : bhh_f;

  __shared__ float whl[12][512];
  __shared__ float hl2[2][64][260];
  __shared__ float hb[64][4];

#pragma unroll
  for (int it = 0; it < 6; ++it) {
    int flat = tid + 256 * it;
    int wrow = flat >> 7;
    int c4   = flat & 127;
    int tyw  = wrow / 3, g = wrow % 3;
    *(f32x4*)&whl[wrow][4 * c4] =
        *(const f32x4*)&Whh[(size_t)(g * HDIM + 4 * ub + tyw) * HDIM + 4 * c4];
  }
  __syncthreads();

  const float br = bhh[u];
  const float bz = bhh[512 + u];
  const float bn = bhh[1024 + u];
  const float* wR = &whl[ty * 3 + 0][0];
  const float* wZ = &whl[ty * 3 + 1][0];
  const float* wN = &whl[ty * 3 + 2][0];
  const int uhalf = u >> 8, ulo = u & 255;
  const int arr_line = (16 * d + (w & 15)) << 4;

  float ir, iz, in_;
  {
    const float* gb = gi + ((size_t)d * nsteps) * 3 * HDIM * BATCH;
    ir  = gb[((size_t)0 * HDIM + u) * BATCH + tx];
    iz  = gb[((size_t)1 * HDIM + u) * BATCH + tx];
    in_ = gb[((size_t)2 * HDIM + u) * BATCH + tx];
  }

  for (int l = 0; l < nsteps; ++l) {
    const int gs      = step0 + l;
    const int t_store = (d == 0) ? gs : (S_LEN - 1 - gs);
    const int t_prev  = (d == 0) ? (gs - 1) : (S_LEN - gs);

    float aR = 0.f, aZ = 0.f, aN = 0.f, hp = 0.f;

    if (gs > 0) {
      const float* hpg = hs + ((size_t)d * S_LEN + t_prev) * HDIM * BATCH;
      f32x4 buf[32];
#pragma unroll
      for (int j = 0; j < 32; ++j) {
        int half = j >> 4;
        int flat = tid + 256 * (j & 15);
        ld_b128_sc(&buf[j], &hpg[(size_t)(flat >> 6) * HDIM + half * 256 + 4 * (flat & 63)]);
      }
      asm volatile("s_waitcnt vmcnt(16)" ::: "memory");
      __builtin_amdgcn_sched_barrier(0);
#pragma unroll
      for (int j = 0; j < 16; ++j) {
        int flat = tid + 256 * j;
        *(f32x4*)&hl2[0][flat >> 6][4 * (flat & 63)] = buf[j];
      }
      __syncthreads();

      if (uhalf == 0) hp = hl2[0][tx][ulo];
      {
        const float* hrow = &hl2[0][tx][0];
#pragma unroll 4
        for (int kk = 0; kk < 256; kk += 4) {
          f32x4 h4  = *(const f32x4*)&hrow[kk];
          f32x4 w4r = *(const f32x4*)&wR[kk];
          f32x4 w4z = *(const f32x4*)&wZ[kk];
          f32x4 w4n = *(const f32x4*)&wN[kk];
          aR += h4.x * w4r.x + h4.y * w4r.y + h4.z * w4r.z + h4.w * w4r.w;
          aZ += h4.x * w4z.x + h4.y * w4z.y + h4.z * w4z.z + h4.w * w4z.w;
          aN += h4.x * w4n.x + h4.y * w4n.y + h4.z * w4n.z + h4.w * w4n.w;
        }
      }

      asm volatile("s_waitcnt vmcnt(0)" ::: "memory");
      __builtin_amdgcn_sched_barrier(0);
#pragma unroll
      for (int j = 16; j < 32; ++j) {
        int flat = tid + 256 * (j & 15);
        *(f32x4*)&hl2[1][flat >> 6][4 * (flat & 63)] = buf[j];
      }
      __syncthreads();

      if (uhalf == 1) hp = hl2[1][tx][ulo];
      {
        const float* hrow = &hl2[1][tx][0];
#pragma unroll 4
        for (int kk = 0; kk < 256; kk += 4) {
          f32x4 h4  = *(const f32x4*)&hrow[kk];
          f32x4 w4r = *(const f32x4*)&wR[256 + kk];
          f32x4 w4z = *(const f32x4*)&wZ[256 + kk];
          f32x4 w4n = *(const f32x4*)&wN[256 + kk];
          aR += h4.x * w4r.x + h4.y * w4r.y + h4.z * w4r.z + h4.w * w4r.w;
          aZ += h4.x * w4z.x + h4.y * w4z.y + h4.z * w4z.z + h4.w * w4z.w;
          aN += h4.x * w4n.x + h4.y * w4n.y + h4.z * w4n.z + h4.w * w4n.w;
        }
      }
    }

    float r  = 1.f / (1.f + expf(-(ir + aR + br)));
    float zg = 1.f / (1.f + expf(-(iz + aZ + bz)));
    float n  = tanhf(in_ + r * (aN + bn));
    float hn = (1.f - zg) * n + zg * hp;

    __syncthreads();
    hb[tx][ty] = hn;
    __syncthreads();
    if (tid < 64) {
      f32x4 v = *(const f32x4*)&hb[tid][0];
      st_b128_sc(&hs[(((size_t)d * S_LEN + t_store) * BATCH + tid) * HDIM + 4 * ub], v);
      asm volatile("s_waitcnt vmcnt(0)" ::: "memory");
    }
    if (tid == 0)
      __hip_atomic_fetch_add(&cnt[arr_line], 1u,
                             __ATOMIC_RELAXED, __HIP_MEMORY_SCOPE_AGENT);
    if (l + 1 < nsteps) {
      const float* gb = gi + ((size_t)d * nsteps + l + 1) * 3 * HDIM * BATCH;
      ir  = gb[((size_t)0 * HDIM + u) * BATCH + tx];
      iz  = gb[((size_t)1 * HDIM + u) * BATCH + tx];
      in_ = gb[((size_t)2 * HDIM + u) * BATCH + tx];
    }
    if (tid < 16) {
      unsigned tgt = 8u * (unsigned)(gs + 1);
      while (__hip_atomic_load(&cnt[(16 * d + tid) << 4],
                               __ATOMIC_RELAXED, __HIP_MEMORY_SCOPE_AGENT) < tgt)
        __builtin_amdgcn_s_sleep(1);
    }
    __syncthreads();
  }
}

// ---------------- Phase C: pz / z ----------------
__global__ __launch_bounds__(256) void pz_kernel(
    const float* __restrict__ hs, const float* __restrict__ zW,
    const float* __restrict__ zb_, const float* __restrict__ noise,
    float* __restrict__ out)
{
  const int gtid = blockIdx.x * 256 + threadIdx.x;
  const int wave = gtid >> 6;
  const int lane = threadIdx.x & 63;
  const float zb = zb_[0];
  float4 w1 = *(const float4*)&zW[lane * 8];
  float4 w2 = *(const float4*)&zW[lane * 8 + 4];
  float4 w3 = *(const float4*)&zW[512 + lane * 8];
  float4 w4 = *(const float4*)&zW[512 + lane * 8 + 4];
  for (int r = wave; r < S_LEN * BATCH; r += 1024) {
    const float* hf  = hs + (size_t)r * HDIM;
    const float* hbk = hs + (size_t)(S_LEN * BATCH + r) * HDIM;
    float4 a1 = *(const float4*)&hf[lane * 8];
    float4 a2 = *(const float4*)&hf[lane * 8 + 4];
    float4 b1 = *(const float4*)&hbk[lane * 8];
    float4 b2 = *(const float4*)&hbk[lane * 8 + 4];
    float acc = a1.x * w1.x + a1.y * w1.y + a1.z * w1.z + a1.w * w1.w
              + a2.x * w2.x + a2.y * w2.y + a2.z * w2.z + a2.w * w2.w
              + b1.x * w3.x + b1.y * w3.y + b1.z * w3.z + b1.w * w3.w
              + b2.x * w4.x + b2.y * w4.y + b2.z * w4.z + b2.w * w4.w;
#pragma unroll
    for (int off = 32; off > 0; off >>= 1) acc += __shfl_down(acc, off, 64);
    if (lane == 0) {
      float p = 1.f / (1.f + expf(-(acc + zb)));
      out[r] = p;
      out[S_LEN * BATCH + r] = (noise[r] < p) ? 1.f : 0.f;
    }
  }
}

// ---------------- Phase D: per-column stable compaction ----------------
__global__ __launch_bounds__(256) void rat_kernel(
    const int* __restrict__ sent, float* __restrict__ out)
{
  const int b = blockIdx.x;
  const int s = threadIdx.x;
  __shared__ int ps[256];
  const int z = (out[S_LEN * BATCH + s * BATCH + b] > 0.5f) ? 1 : 0;
  ps[s] = z;
  __syncthreads();
#pragma unroll
  for (int off = 1; off < 256; off <<= 1) {
    int v = (s >= off) ? ps[s - off] : 0;
    __syncthreads();
    ps[s] += v;
    __syncthreads();
  }
  const int incl  = ps[s];
  const int total = ps[255];
  const int pos   = incl - z;
  if (z) out[2 * S_LEN * BATCH + pos * BATCH + b] = (float)sent[s * BATCH + b];
  if (s >= total) out[2 * S_LEN * BATCH + s * BATCH + b] = 0.f;
  if (s == 0) out[3 * S_LEN * BATCH + b] = (float)total;
}

extern "C" void kernel_launch(void* const* d_in, const int* in_sizes, int n_in,
                              void* d_out, int out_size, void* d_ws, size_t ws_size,
                              hipStream_t stream)
{
  const int*   sent  = (const int*)  d_in[0];
  const float* noise = (const float*)d_in[1];
  const float* emb   = (const float*)d_in[2];
  const float* Wih_f = (const float*)d_in[3];
  const float* Whh_f = (const float*)d_in[4];
  const float* bih_f = (const float*)d_in[5];
  const float* bhh_f = (const float*)d_in[6];
  const float* Wih_b = (const float*)d_in[7];
  const float* Whh_b = (const float*)d_in[8];
  const float* bih_b = (const float*)d_in[9];
  const float* bhh_b = (const float*)d_in[10];
  const float* zW    = (const float*)d_in[11];
  const float* zb    = (const float*)d_in[12];
  float* out = (float*)d_out;

  float* base = (float*)d_ws;
  unsigned* cnt = (unsigned*)base;                         // 4 KB reserved
  float* hs = base + 1024;                                 // 67.1 MB
  float* gi = hs + (size_t)2 * S_LEN * HDIM * BATCH;       // fallback only

  const size_t HS_BYTES = (size_t)2 * S_LEN * HDIM * BATCH * 4;

  (void)hipMemsetAsync(cnt, 0, 4096, stream);
  if (ws_size >= 4096 + HS_BYTES) {
    mega_kernel<<<dim3(256), 256, 0, stream>>>(
        sent, emb, Wih_f, bih_f, Wih_b, bih_b, hs,
        Whh_f, bhh_f, Whh_b, bhh_b, cnt);
  } else {
    for (int c = 0; c < 4; ++c) {
      gi_gemm<<<dim3(32, 12, 2), 512, 0, stream>>>(
          sent, emb, Wih_f, bih_f, Wih_b, bih_b, gi, 64 * c, 0, 64);
      scan_kernel<<<dim3(256), 256, 0, stream>>>(
          gi, hs, Whh_f, bhh_f, Whh_b, bhh_b, cnt, 64 * c, 64);
    }
  }
  pz_kernel<<<dim3(256), 256, 0, stream>>>(hs, zW, zb, noise, out);
  rat_kernel<<<dim3(BATCH), 256, 0, stream>>>(sent, out);
}

// Round 17
// 4136.941 us; speedup vs baseline: 1.4041x; 1.4041x over previous
//
#include <hip/hip_runtime.h>
#include <math.h>

#define S_LEN 256
#define BATCH 64
#define EDIM  256
#define HDIM  512

typedef float f32x4 __attribute__((ext_vector_type(4)));

// ---- cache-bypassing (coherence-point) 16B load/store: sc0 sc1 ----
__device__ __forceinline__ void ld_b128_sc(f32x4* v, const float* p) {
  asm volatile("global_load_dwordx4 %0, %1, off sc0 sc1"
               : "=v"(*v) : "v"(p) : "memory");
}
__device__ __forceinline__ void st_b128_sc(float* p, f32x4 v) {
  asm volatile("global_store_dwordx4 %0, %1, off sc0 sc1"
               :: "v"(p), "v"(v) : "memory");
}

// ---------------- Phase A (fallback only): gi = emb[sent] @ Wih^T + bih ----
__global__ __launch_bounds__(512) void gi_gemm(
    const int* __restrict__ sent, const float* __restrict__ emb,
    const float* __restrict__ Wih_f, const float* __restrict__ bih_f,
    const float* __restrict__ Wih_b, const float* __restrict__ bih_b,
    float* __restrict__ gi, int abs_base, int buf_base, int dstride)
{
  const int d  = blockIdx.z;
  const int bx = blockIdx.x;
  const int by = blockIdx.y;
  const float* W    = d ? Wih_b : Wih_f;
  const float* bias = d ? bih_b : bih_f;

  __shared__ int    tok[128];
  __shared__ float4 As4[128][8];
  __shared__ float4 Bs4[128][8];

  const int tid = threadIdx.x;
  if (tid < 128) {
    int s_lc = 2 * bx + (tid >> 6);
    int slot = abs_base + s_lc;
    int srow = (d == 0) ? slot : (S_LEN - 1 - slot);
    tok[tid] = sent[srow * BATCH + (tid & 63)];
  }

  float acc[8][4];
#pragma unroll
  for (int i = 0; i < 8; ++i)
#pragma unroll
    for (int j = 0; j < 4; ++j) acc[i][j] = 0.f;

  const int tb = tid & 15;
  const int tn = tid >> 4;

  for (int kc = 0; kc < 8; ++kc) {
    __syncthreads();
#pragma unroll
    for (int it = 0; it < 2; ++it) {
      int flat = tid + 512 * it;
      int row  = flat >> 3;
      int k4   = flat & 7;
      int sw   = k4 ^ (row & 7) ^ ((row >> 3) & 7);
      As4[row][sw] = *(const float4*)&emb[(size_t)tok[row] * EDIM + kc * 32 + 4 * k4];
      Bs4[row][sw] = *(const float4*)&W[(size_t)(by * 128 + row) * EDIM + kc * 32 + 4 * k4];
    }
    __syncthreads();
#pragma unroll
    for (int k4 = 0; k4 < 8; ++k4) {
      float4 a[8];
#pragma unroll
      for (int i = 0; i < 8; ++i)
        a[i] = As4[8 * tb + i][k4 ^ i ^ (tb & 7)];
#pragma unroll
      for (int j = 0; j < 4; ++j) {
        int r = 4 * tn + j;
        float4 bf = Bs4[r][k4 ^ (r & 7) ^ ((r >> 3) & 7)];
#pragma unroll
        for (int i = 0; i < 8; ++i)
          acc[i][j] += a[i].x * bf.x + a[i].y * bf.y
                     + a[i].z * bf.z + a[i].w * bf.w;
      }
    }
  }

  const int s_lc = 2 * bx + (tb >> 3);
  const int brow = 8 * (tb & 7);
#pragma unroll
  for (int j = 0; j < 4; ++j) {
    int n = by * 128 + 4 * tn + j;
    float bs = bias[n];
    int g = n >> 9, u = n & 511;
    size_t base = ((((size_t)d * dstride + buf_base + s_lc) * 3 + g) * HDIM + u) * BATCH + brow;
    float4 v0 = { acc[0][j] + bs, acc[1][j] + bs, acc[2][j] + bs, acc[3][j] + bs };
    float4 v1 = { acc[4][j] + bs, acc[5][j] + bs, acc[6][j] + bs, acc[7][j] + bs };
    *(float4*)&gi[base]     = v0;
    *(float4*)&gi[base + 4] = v1;
  }
}

#define GBUF ((size_t)2 * 64 * 3 * HDIM * BATCH)   // fallback gi buffer (floats)

// ---------------- Phase B: FULLY-FUSED scan; gi hidden under dot-HALF1 ------
// 256 WGs x 256 thr, ONE dispatch, no gi workspace. v11: R16's fused-gi
// regression was vmcnt queue poisoning -- gi e-loads in dot-half0 forced
// draining the older, still-in-flight h-half1 loads (in-order VMEM
// retirement). Fix: fuse gi(gs+1) into dot-HALF1, where the per-step
// vmcnt(0) has already emptied the queue; the 64 cached e-loads pipeline
// freely under the compiler's incremental waits and overlap the LDS dot.
// Both accumulation chains keep their exact element order -> bitwise-
// identical outputs (R14/R15/R16 all verified absmax 0.0). Token for the
// next fused gi is prefetched one step ahead (barrier window).
__global__ __launch_bounds__(256, 1) void mega_kernel(
    const int* __restrict__ sent, const float* __restrict__ emb,
    const float* __restrict__ Wih_f, const float* __restrict__ bih_f,
    const float* __restrict__ Wih_b, const float* __restrict__ bih_b,
    float* __restrict__ hs,
    const float* __restrict__ Whh_f, const float* __restrict__ bhh_f,
    const float* __restrict__ Whh_b, const float* __restrict__ bhh_b,
    unsigned* cnt)
{
  const int w   = blockIdx.x;
  const int d   = w >> 7;
  const int ub  = w & 127;
  const int tid = threadIdx.x;
  const int tx  = tid & 63;
  const int ty  = __builtin_amdgcn_readfirstlane(tid >> 6);   // 0..3 wave-uniform
  const int u   = 4 * ub + ty;

  const float* Whh = d ? Whh_b : Whh_f;
  const float* bhh = d ? bhh_b : bhh_f;
  const float* Wih = d ? Wih_b : Wih_f;
  const float* bih = d ? bih_b : bih_f;

  __shared__ float whl[12][512];    // Whh rows (24.6 KB)
  __shared__ float wihl[12][256];   // Wih rows (12.3 KB)
  __shared__ float hl[64][260];     // h(t-1), halves sequentially (66.5 KB)
  __shared__ float hb[64][4];

  // stage Whh rows (once)
#pragma unroll
  for (int it = 0; it < 6; ++it) {
    int flat = tid + 256 * it;          // 0..1535 float4s
    int wrow = flat >> 7;
    int c4   = flat & 127;
    int tyw  = wrow / 3, g = wrow % 3;
    *(f32x4*)&whl[wrow][4 * c4] =
        *(const f32x4*)&Whh[(size_t)(g * HDIM + 4 * ub + tyw) * HDIM + 4 * c4];
  }
  // stage Wih rows (once)
#pragma unroll
  for (int it = 0; it < 3; ++it) {
    int flat = tid + 256 * it;          // 0..767 float4s
    int wrow = flat >> 6;
    int c4   = flat & 63;
    int tyw  = wrow / 3, g = wrow % 3;
    *(f32x4*)&wihl[wrow][4 * c4] =
        *(const f32x4*)&Wih[(size_t)(g * HDIM + 4 * ub + tyw) * EDIM + 4 * c4];
  }
  __syncthreads();

  const float br = bhh[u];
  const float bz = bhh[512 + u];
  const float bn = bhh[1024 + u];
  const float bir = bih[u], biz = bih[512 + u], bin = bih[1024 + u];
  const float* wR = &whl[ty * 3 + 0][0];
  const float* wZ = &whl[ty * 3 + 1][0];
  const float* wN = &whl[ty * 3 + 2][0];
  const float* iR = &wihl[ty * 3 + 0][0];
  const float* iZ = &wihl[ty * 3 + 1][0];
  const float* iN = &wihl[ty * 3 + 2][0];
  const int uhalf = u >> 8, ulo = u & 255;
  const int arr_line = (16 * d + (w & 15)) << 4;

  float ir, iz, in_;
#define INLINE_GI(S)                                                        \
  {                                                                         \
    const int srow = (d == 0) ? (S) : (S_LEN - 1 - (S));                    \
    const int tk   = sent[srow * BATCH + tx];                               \
    const float* ep = emb + (size_t)tk * EDIM;                              \
    float g0 = 0.f, g1 = 0.f, g2 = 0.f;                                     \
    _Pragma("unroll 8")                                                     \
    for (int m = 0; m < 64; ++m) {                                          \
      f32x4 e  = *(const f32x4*)&ep[4 * m];                                 \
      f32x4 wa = *(const f32x4*)&iR[4 * m];                                 \
      f32x4 wb = *(const f32x4*)&iZ[4 * m];                                 \
      f32x4 wc = *(const f32x4*)&iN[4 * m];                                 \
      g0 += e.x * wa.x + e.y * wa.y + e.z * wa.z + e.w * wa.w;              \
      g1 += e.x * wb.x + e.y * wb.y + e.z * wb.z + e.w * wb.w;              \
      g2 += e.x * wc.x + e.y * wc.y + e.z * wc.z + e.w * wc.w;              \
    }                                                                       \
    ir = g0 + bir; iz = g1 + biz; in_ = g2 + bin;                           \
  }

  INLINE_GI(0)                         // step 0's gi, in registers
  int tkn = 0;                         // token for the next fused gi slot

  for (int gs = 0; gs < S_LEN; ++gs) {
    const int t_store = (d == 0) ? gs : (S_LEN - 1 - gs);
    const int t_prev  = (d == 0) ? (gs - 1) : (S_LEN - gs);

    float aR = 0.f, aZ = 0.f, aN = 0.f, hp = 0.f;
    float gn0 = 0.f, gn1 = 0.f, gn2 = 0.f;
    bool have_gn = false;

    if (gs > 0) {
      const float* hpg = hs + ((size_t)d * S_LEN + t_prev) * HDIM * BATCH;
      f32x4 buf[32];
#pragma unroll
      for (int j = 0; j < 32; ++j) {
        int half = j >> 4;
        int flat = tid + 256 * (j & 15);
        ld_b128_sc(&buf[j], &hpg[(size_t)(flat >> 6) * HDIM + half * 256 + 4 * (flat & 63)]);
      }
      asm volatile("s_waitcnt vmcnt(16)" ::: "memory");   // half 0 arrived
      __builtin_amdgcn_sched_barrier(0);
#pragma unroll
      for (int j = 0; j < 16; ++j) {
        int flat = tid + 256 * j;
        *(f32x4*)&hl[flat >> 6][4 * (flat & 63)] = buf[j];
      }
      __syncthreads();

      if (uhalf == 0) hp = hl[tx][ulo];
      {
        // plain dot-half0 (h-half1 loads still in flight -- keep VMEM clean)
        const float* hrow = &hl[tx][0];
#pragma unroll 4
        for (int kk = 0; kk < 256; kk += 4) {
          f32x4 h4  = *(const f32x4*)&hrow[kk];
          f32x4 w4r = *(const f32x4*)&wR[kk];
          f32x4 w4z = *(const f32x4*)&wZ[kk];
          f32x4 w4n = *(const f32x4*)&wN[kk];
          aR += h4.x * w4r.x + h4.y * w4r.y + h4.z * w4r.z + h4.w * w4r.w;
          aZ += h4.x * w4z.x + h4.y * w4z.y + h4.z * w4z.z + h4.w * w4z.w;
          aN += h4.x * w4n.x + h4.y * w4n.y + h4.z * w4n.z + h4.w * w4n.w;
        }
      }
      __syncthreads();                                    // half-0 reads done
      asm volatile("s_waitcnt vmcnt(0)" ::: "memory");    // queue now EMPTY
      __builtin_amdgcn_sched_barrier(0);
#pragma unroll
      for (int j = 16; j < 32; ++j) {
        int flat = tid + 256 * (j & 15);
        *(f32x4*)&hl[flat >> 6][4 * (flat & 63)] = buf[j];
      }
      __syncthreads();

      if (uhalf == 1) hp = hl[tx][ulo];
      {
        const float* hrow = &hl[tx][0];
        if (gs + 1 < S_LEN) {
          // ---- FUSED dot-half1 + gi(gs+1): empty VMEM queue -> e-loads
          // pipeline under compiler waits; chains keep exact element order.
          const float* ep = emb + (size_t)tkn * EDIM;
#pragma unroll 4
          for (int m = 0; m < 64; ++m) {
            f32x4 h4  = *(const f32x4*)&hrow[4 * m];
            f32x4 w4r = *(const f32x4*)&wR[256 + 4 * m];
            f32x4 w4z = *(const f32x4*)&wZ[256 + 4 * m];
            f32x4 w4n = *(const f32x4*)&wN[256 + 4 * m];
            aR += h4.x * w4r.x + h4.y * w4r.y + h4.z * w4r.z + h4.w * w4r.w;
            aZ += h4.x * w4z.x + h4.y * w4z.y + h4.z * w4z.z + h4.w * w4z.w;
            aN += h4.x * w4n.x + h4.y * w4n.y + h4.z * w4n.z + h4.w * w4n.w;
            f32x4 e  = *(const f32x4*)&ep[4 * m];
            f32x4 wa = *(const f32x4*)&iR[4 * m];
            f32x4 wb = *(const f32x4*)&iZ[4 * m];
            f32x4 wc = *(const f32x4*)&iN[4 * m];
            gn0 += e.x * wa.x + e.y * wa.y + e.z * wa.z + e.w * wa.w;
            gn1 += e.x * wb.x + e.y * wb.y + e.z * wb.z + e.w * wb.w;
            gn2 += e.x * wc.x + e.y * wc.y + e.z * wc.z + e.w * wc.w;
          }
          have_gn = true;
        } else {
          // plain dot-half1 (last step)
#pragma unroll 4
          for (int kk = 0; kk < 256; kk += 4) {
            f32x4 h4  = *(const f32x4*)&hrow[kk];
            f32x4 w4r = *(const f32x4*)&wR[256 + kk];
            f32x4 w4z = *(const f32x4*)&wZ[256 + kk];
            f32x4 w4n = *(const f32x4*)&wN[256 + kk];
            aR += h4.x * w4r.x + h4.y * w4r.y + h4.z * w4r.z + h4.w * w4r.w;
            aZ += h4.x * w4z.x + h4.y * w4z.y + h4.z * w4z.z + h4.w * w4z.w;
            aN += h4.x * w4n.x + h4.y * w4n.y + h4.z * w4n.z + h4.w * w4n.w;
          }
        }
      }
    }

    float r  = 1.f / (1.f + expf(-(ir + aR + br)));
    float zg = 1.f / (1.f + expf(-(iz + aZ + bz)));
    float n  = tanhf(in_ + r * (aN + bn));
    float hn = (1.f - zg) * n + zg * hp;

    // commit next step's gi (computed in the fused half1)
    if (have_gn) { ir = gn0 + bir; iz = gn1 + biz; in_ = gn2 + bin; }

    __syncthreads();
    hb[tx][ty] = hn;
    __syncthreads();
    if (tid < 64) {
      f32x4 v = *(const f32x4*)&hb[tid][0];
      st_b128_sc(&hs[(((size_t)d * S_LEN + t_store) * BATCH + tid) * HDIM + 4 * ub], v);
      asm volatile("s_waitcnt vmcnt(0)" ::: "memory");
    }
    if (tid == 0)
      __hip_atomic_fetch_add(&cnt[arr_line], 1u,
                             __ATOMIC_RELAXED, __HIP_MEMORY_SCOPE_AGENT);

    if (gs == 0) INLINE_GI(1)          // only step 0 lacks a dot to fuse into

    // prefetch the token for the NEXT step's fused gi (slot gs+2)
    if (gs + 2 < S_LEN)
      tkn = sent[((d == 0) ? (gs + 2) : (S_LEN - 3 - gs)) * BATCH + tx];

    // per-direction barrier poll
    if (tid < 16) {
      unsigned tgt = 8u * (unsigned)(gs + 1);
      while (__hip_atomic_load(&cnt[(16 * d + tid) << 4],
                               __ATOMIC_RELAXED, __HIP_MEMORY_SCOPE_AGENT) < tgt)
        __builtin_amdgcn_s_sleep(1);
    }
    __syncthreads();
  }
#undef INLINE_GI
}

// ---------------- Fallback classic scan (R8/R13) for small ws ----------------
__global__ __launch_bounds__(256, 1) void scan_kernel(
    const float* __restrict__ gi, float* __restrict__ hs,
    const float* __restrict__ Whh_f, const float* __restrict__ bhh_f,
    const float* __restrict__ Whh_b, const float* __restrict__ bhh_b,
    unsigned* cnt, int step0, int nsteps)
{
  const int w   = blockIdx.x;
  const int d   = w >> 7;
  const int ub  = w & 127;
  const int tid = threadIdx.x;
  const int tx  = tid & 63;
  const int ty  = __builtin_amdgcn_readfirstlane(tid >> 6);
  const int u   = 4 * ub + ty;

  const float* Whh = d ? Whh_b : Whh_f;
  const float* bhh = d ? bhh_b : bhh_f;

  __shared__ float whl[12][512];
  __shared__ float hl2[2][64][260];
  __shared__ float hb[64][4];

#pragma unroll
  for (int it = 0; it < 6; ++it) {
    int flat = tid + 256 * it;
    int wrow = flat >> 7;
    int c4   = flat & 127;
    int tyw  = wrow / 3, g = wrow % 3;
    *(f32x4*)&whl[wrow][4 * c4] =
        *(const f32x4*)&Whh[(size_t)(g * HDIM + 4 * ub + tyw) * HDIM + 4 * c4];
  }
  __syncthreads();

  const float br = bhh[u];
  const float bz = bhh[512 + u];
  const float bn = bhh[1024 + u];
  const float* wR = &whl[ty * 3 + 0][0];
  const float* wZ = &whl[ty * 3 + 1][0];
  const float* wN = &whl[ty * 3 + 2][0];
  const int uhalf = u >> 8, ulo = u & 255;
  const int arr_line = (16 * d + (w & 15)) << 4;

  float ir, iz, in_;
  {
    const float* gb = gi + ((size_t)d * nsteps) * 3 * HDIM * BATCH;
    ir  = gb[((size_t)0 * HDIM + u) * BATCH + tx];
    iz  = gb[((size_t)1 * HDIM + u) * BATCH + tx];
    in_ = gb[((size_t)2 * HDIM + u) * BATCH + tx];
  }

  for (int l = 0; l < nsteps; ++l) {
    const int gs      = step0 + l;
    const int t_store = (d == 0) ? gs : (S_LEN - 1 - gs);
    const int t_prev  = (d == 0) ? (gs - 1) : (S_LEN - gs);

    float aR = 0.f, aZ = 0.f, aN = 0.f, hp = 0.f;

    if (gs > 0) {
      const float* hpg = hs + ((size_t)d * S_LEN + t_prev) * HDIM * BATCH;
      f32x4 buf[32];
#pragma unroll
      for (int j = 0; j < 32; ++j) {
        int half = j >> 4;
        int flat = tid + 256 * (j & 15);
        ld_b128_sc(&buf[j], &hpg[(size_t)(flat >> 6) * HDIM + half * 256 + 4 * (flat & 63)]);
      }
      asm volatile("s_waitcnt vmcnt(16)" ::: "memory");
      __builtin_amdgcn_sched_barrier(0);
#pragma unroll
      for (int j = 0; j < 16; ++j) {
        int flat = tid + 256 * j;
        *(f32x4*)&hl2[0][flat >> 6][4 * (flat & 63)] = buf[j];
      }
      __syncthreads();

      if (uhalf == 0) hp = hl2[0][tx][ulo];
      {
        const float* hrow = &hl2[0][tx][0];
#pragma unroll 4
        for (int kk = 0; kk < 256; kk += 4) {
          f32x4 h4  = *(const f32x4*)&hrow[kk];
          f32x4 w4r = *(const f32x4*)&wR[kk];
          f32x4 w4z = *(const f32x4*)&wZ[kk];
          f32x4 w4n = *(const f32x4*)&wN[kk];
          aR += h4.x * w4r.x + h4.y * w4r.y + h4.z * w4r.z + h4.w * w4r.w;
          aZ += h4.x * w4z.x + h4.y * w4z.y + h4.z * w4z.z + h4.w * w4z.w;
          aN += h4.x * w4n.x + h4.y * w4n.y + h4.z * w4n.z + h4.w * w4n.w;
        }
      }

      asm volatile("s_waitcnt vmcnt(0)" ::: "memory");
      __builtin_amdgcn_sched_barrier(0);
#pragma unroll
      for (int j = 16; j < 32; ++j) {
        int flat = tid + 256 * (j & 15);
        *(f32x4*)&hl2[1][flat >> 6][4 * (flat & 63)] = buf[j];
      }
      __syncthreads();

      if (uhalf == 1) hp = hl2[1][tx][ulo];
      {
        const float* hrow = &hl2[1][tx][0];
#pragma unroll 4
        for (int kk = 0; kk < 256; kk += 4) {
          f32x4 h4  = *(const f32x4*)&hrow[kk];
          f32x4 w4r = *(const f32x4*)&wR[256 + kk];
          f32x4 w4z = *(const f32x4*)&wZ[256 + kk];
          f32x4 w4n = *(const f32x4*)&wN[256 + kk];
          aR += h4.x * w4r.x + h4.y * w4r.y + h4.z * w4r.z + h4.w * w4r.w;
          aZ += h4.x * w4z.x + h4.y * w4z.y + h4.z * w4z.z + h4.w * w4z.w;
          aN += h4.x * w4n.x + h4.y * w4n.y + h4.z * w4n.z + h4.w * w4n.w;
        }
      }
    }

    float r  = 1.f / (1.f + expf(-(ir + aR + br)));
    float zg = 1.f / (1.f + expf(-(iz + aZ + bz)));
    float n  = tanhf(in_ + r * (aN + bn));
    float hn = (1.f - zg) * n + zg * hp;

    __syncthreads();
    hb[tx][ty] = hn;
    __syncthreads();
    if (tid < 64) {
      f32x4 v = *(const f32x4*)&hb[tid][0];
      st_b128_sc(&hs[(((size_t)d * S_LEN + t_store) * BATCH + tid) * HDIM + 4 * ub], v);
      asm volatile("s_waitcnt vmcnt(0)" ::: "memory");
    }
    if (tid == 0)
      __hip_atomic_fetch_add(&cnt[arr_line], 1u,
                             __ATOMIC_RELAXED, __HIP_MEMORY_SCOPE_AGENT);
    if (l + 1 < nsteps) {
      const float* gb = gi + ((size_t)d * nsteps + l + 1) * 3 * HDIM * BATCH;
      ir  = gb[((size_t)0 * HDIM + u) * BATCH + tx];
      iz  = gb[((size_t)1 * HDIM + u) * BATCH + tx];
      in_ = gb[((size_t)2 * HDIM + u) * BATCH + tx];
    }
    if (tid < 16) {
      unsigned tgt = 8u * (unsigned)(gs + 1);
      while (__hip_atomic_load(&cnt[(16 * d + tid) << 4],
                               __ATOMIC_RELAXED, __HIP_MEMORY_SCOPE_AGENT) < tgt)
        __builtin_amdgcn_s_sleep(1);
    }
    __syncthreads();
  }
}

// ---------------- Phase C: pz / z ----------------
__global__ __launch_bounds__(256) void pz_kernel(
    const float* __restrict__ hs, const float* __restrict__ zW,
    const float* __restrict__ zb_, const float* __restrict__ noise,
    float* __restrict__ out)
{
  const int gtid = blockIdx.x * 256 + threadIdx.x;
  const int wave = gtid >> 6;
  const int lane = threadIdx.x & 63;
  const float zb = zb_[0];
  float4 w1 = *(const float4*)&zW[lane * 8];
  float4 w2 = *(const float4*)&zW[lane * 8 + 4];
  float4 w3 = *(const float4*)&zW[512 + lane * 8];
  float4 w4 = *(const float4*)&zW[512 + lane * 8 + 4];
  for (int r = wave; r < S_LEN * BATCH; r += 1024) {
    const float* hf  = hs + (size_t)r * HDIM;
    const float* hbk = hs + (size_t)(S_LEN * BATCH + r) * HDIM;
    float4 a1 = *(const float4*)&hf[lane * 8];
    float4 a2 = *(const float4*)&hf[lane * 8 + 4];
    float4 b1 = *(const float4*)&hbk[lane * 8];
    float4 b2 = *(const float4*)&hbk[lane * 8 + 4];
    float acc = a1.x * w1.x + a1.y * w1.y + a1.z * w1.z + a1.w * w1.w
              + a2.x * w2.x + a2.y * w2.y + a2.z * w2.z + a2.w * w2.w
              + b1.x * w3.x + b1.y * w3.y + b1.z * w3.z + b1.w * w3.w
              + b2.x * w4.x + b2.y * w4.y + b2.z * w4.z + b2.w * w4.w;
#pragma unroll
    for (int off = 32; off > 0; off >>= 1) acc += __shfl_down(acc, off, 64);
    if (lane == 0) {
      float p = 1.f / (1.f + expf(-(acc + zb)));
      out[r] = p;
      out[S_LEN * BATCH + r] = (noise[r] < p) ? 1.f : 0.f;
    }
  }
}

// ---------------- Phase D: per-column stable compaction ----------------
__global__ __launch_bounds__(256) void rat_kernel(
    const int* __restrict__ sent, float* __restrict__ out)
{
  const int b = blockIdx.x;
  const int s = threadIdx.x;
  __shared__ int ps[256];
  const int z = (out[S_LEN * BATCH + s * BATCH + b] > 0.5f) ? 1 : 0;
  ps[s] = z;
  __syncthreads();
#pragma unroll
  for (int off = 1; off < 256; off <<= 1) {
    int v = (s >= off) ? ps[s - off] : 0;
    __syncthreads();
    ps[s] += v;
    __syncthreads();
  }
  const int incl  = ps[s];
  const int total = ps[255];
  const int pos   = incl - z;
  if (z) out[2 * S_LEN * BATCH + pos * BATCH + b] = (float)sent[s * BATCH + b];
  if (s >= total) out[2 * S_LEN * BATCH + s * BATCH + b] = 0.f;
  if (s == 0) out[3 * S_LEN * BATCH + b] = (float)total;
}

extern "C" void kernel_launch(void* const* d_in, const int* in_sizes, int n_in,
                              void* d_out, int out_size, void* d_ws, size_t ws_size,
                              hipStream_t stream)
{
  const int*   sent  = (const int*)  d_in[0];
  const float* noise = (const float*)d_in[1];
  const float* emb   = (const float*)d_in[2];
  const float* Wih_f = (const float*)d_in[3];
  const float* Whh_f = (const float*)d_in[4];
  const float* bih_f = (const float*)d_in[5];
  const float* bhh_f = (const float*)d_in[6];
  const float* Wih_b = (const float*)d_in[7];
  const float* Whh_b = (const float*)d_in[8];
  const float* bih_b = (const float*)d_in[9];
  const float* bhh_b = (const float*)d_in[10];
  const float* zW    = (const float*)d_in[11];
  const float* zb    = (const float*)d_in[12];
  float* out = (float*)d_out;

  float* base = (float*)d_ws;
  unsigned* cnt = (unsigned*)base;                         // 4 KB reserved
  float* hs = base + 1024;                                 // 67.1 MB
  float* gi = hs + (size_t)2 * S_LEN * HDIM * BATCH;       // fallback only

  const size_t HS_BYTES = (size_t)2 * S_LEN * HDIM * BATCH * 4;

  (void)hipMemsetAsync(cnt, 0, 4096, stream);
  if (ws_size >= 4096 + HS_BYTES) {
    mega_kernel<<<dim3(256), 256, 0, stream>>>(
        sent, emb, Wih_f, bih_f, Wih_b, bih_b, hs,
        Whh_f, bhh_f, Whh_b, bhh_b, cnt);
  } else {
    for (int c = 0; c < 4; ++c) {
      gi_gemm<<<dim3(32, 12, 2), 512, 0, stream>>>(
          sent, emb, Wih_f, bih_f, Wih_b, bih_b, gi, 64 * c, 0, 64);
      scan_kernel<<<dim3(256), 256, 0, stream>>>(
          gi, hs, Whh_f, bhh_f, Whh_b, bhh_b, cnt, 64 * c, 64);
    }
  }
  pz_kernel<<<dim3(256), 256, 0, stream>>>(hs, zW, zb, noise, out);
  rat_kernel<<<dim3(BATCH), 256, 0, stream>>>(sent, out);
}